// Round 3
// baseline (739.363 us; speedup 1.0000x reference)
//
#include <hip/hip_runtime.h>
#include <stdint.h>
#include <math.h>

#define NA 9
#define NH 128
#define NW 128
#define NTOT (NA*NH*NW)          // 147456
#define PRE_N 6000
#define POST_N 300
#define CAND_CAP 8192
#define NWORDS 94                // ceil(6000/64)
#define SORT_THREADS 512

// ---- ws layout (bytes) ----
constexpr size_t OFF_BOXES = 0;                        // float4 * NTOT      = 2359296
constexpr size_t OFF_KEYS  = OFF_BOXES + (size_t)NTOT * 16;   // u64 * NTOT = 1179648
constexpr size_t OFF_HIST  = OFF_KEYS + (size_t)NTOT * 8;     // uint * 65536 = 262144
constexpr size_t OFF_META  = OFF_HIST + 65536 * 4;            // 64 B
constexpr size_t OFF_CAND  = OFF_META + 64;                   // u64 * CAND_CAP = 65536
constexpr size_t OFF_TIDX  = OFF_CAND + (size_t)CAND_CAP * 8; // uint * PRE_N = 24000
constexpr size_t OFF_SP    = OFF_TIDX + 24000;                // float4 * PRE_N = 96000
constexpr size_t OFF_SD    = OFF_SP + 96000;                  // float4 * PRE_N = 96000
constexpr size_t OFF_SUP   = OFF_SD + 96000;                  // u64 * PRE_N * NWORDS = 4512000

// monotone float -> uint (ascending order preserved, total order incl. -inf)
static __device__ __forceinline__ unsigned int ford(float f) {
    unsigned int b = __float_as_uint(f);
    return b ^ ((b & 0x80000000u) ? 0xFFFFFFFFu : 0x80000000u);
}

__global__ void k_boxes(const float* __restrict__ scores,
                        const float* __restrict__ deltas,
                        const float* __restrict__ anchors,
                        float4* __restrict__ boxes,
                        unsigned long long* __restrict__ keys,
                        unsigned int* __restrict__ hist) {
    int i = blockIdx.x * blockDim.x + threadIdx.x;
    if (i >= NTOT) return;
    int a   = i >> 14;       // / (128*128)
    int rem = i & 16383;
    float4 d  = ((const float4*)deltas)[a * 16384 + rem]; // raw-reshape layout
    float4 an = ((const float4*)anchors)[i];
    // boxes = max(anchors + deltas, 0)
    float x1 = fmaxf(an.x + d.x, 0.0f);
    float y1 = fmaxf(an.y + d.y, 0.0f);
    float bw = fmaxf(an.z + d.z, 0.0f);
    float bh = fmaxf(an.w + d.w, 0.0f);
    float x2 = fminf(x1 + bw - 1.0f, 127.0f);   // uses pre-clamp x1
    float y2 = fminf(y1 + bh - 1.0f, 127.0f);
    x1 = fminf(x1, 127.0f);
    y1 = fminf(y1, 127.0f);
    bw = x2 - x1 + 1.0f;
    bh = y2 - y1 + 1.0f;
    boxes[i] = make_float4(x1, y1, bw, bh);
    bool valid = (bw >= 16.0f) && (bh >= 16.0f);
    float sc = valid ? scores[i] : -INFINITY;
    unsigned int inv = ~ford(sc);               // ascending inv <=> descending score
    keys[i] = ((unsigned long long)inv << 32) | (unsigned int)i;
    // Only valid entries enter the top-k race. Invalid (-inf) entries can
    // never influence the output (V=0 everywhere downstream), so exclude
    // them entirely -> deterministic selection even when valid < PRE_N.
    if (valid) atomicAdd(&hist[inv >> 16], 1u);
}

__global__ void k_findbin(const unsigned int* __restrict__ hist,
                          unsigned int* __restrict__ meta) {
    __shared__ unsigned int part[256];
    int t = threadIdx.x;
    unsigned int s = 0;
    for (int b = t * 256; b < (t + 1) * 256; ++b) s += hist[b];
    part[t] = s;
    __syncthreads();
    if (t == 0) {
        unsigned int total = 0;
        for (int i = 0; i < 256; ++i) total += part[i];
        unsigned int target = (total < PRE_N) ? total : PRE_N;
        unsigned int c = 0;
        int seg = 0;
        if (target > 0) {
            while (c + part[seg] < target) { c += part[seg]; seg++; }
            unsigned int cum = c;
            int b = seg * 256;
            while (cum + hist[b] < target) { cum += hist[b]; b++; }
            meta[0] = (unsigned int)b;  // threshold bin B (valid bins only)
        } else {
            meta[0] = 0;
        }
    }
}

__global__ void k_compact(const unsigned long long* __restrict__ keys,
                          const unsigned int* __restrict__ meta,
                          unsigned long long* __restrict__ cand,
                          unsigned int* __restrict__ cnt) {
    int i = blockIdx.x * blockDim.x + threadIdx.x;
    if (i >= NTOT) return;
    unsigned long long k = keys[i];
    unsigned int bin = (unsigned int)(k >> 48);
    // invalid entries live in bin 0xFF80 (> any valid bin) -> excluded
    if (bin <= meta[0]) {
        unsigned int p = atomicAdd(cnt, 1u);
        if (p < CAND_CAP) cand[p] = k;
    }
}

static __device__ void bitonic8192(unsigned long long* sk, int t) {
    for (int k = 2; k <= CAND_CAP; k <<= 1) {
        for (int j = k >> 1; j > 0; j >>= 1) {
            for (int i = t; i < CAND_CAP; i += SORT_THREADS) {
                int l = i ^ j;
                if (l > i) {
                    unsigned long long a = sk[i], b = sk[l];
                    bool up = ((i & k) == 0);
                    bool sw = up ? (a > b) : (a < b);
                    if (sw) { sk[i] = b; sk[l] = a; }
                }
            }
            __syncthreads();
        }
    }
}

__global__ void __launch_bounds__(SORT_THREADS)
k_sortbuild(const float4* __restrict__ boxes,
            const unsigned int* __restrict__ meta,
            const unsigned long long* __restrict__ cand,
            unsigned int* __restrict__ topidx,
            float4* __restrict__ sP, float4* __restrict__ sD) {
    __shared__ unsigned long long sk[CAND_CAP];   // 64 KiB
    int t = threadIdx.x;
    unsigned int cnt = meta[2];
    if (cnt > CAND_CAP) cnt = CAND_CAP;
    unsigned int nreal = (cnt < PRE_N) ? cnt : PRE_N;  // top-k size actually used
    for (int i = t; i < CAND_CAP; i += SORT_THREADS)
        sk[i] = (i < (int)cnt) ? cand[i] : ~0ull;
    __syncthreads();
    bitonic8192(sk, t);   // ascending => (score desc, idx asc) : top_k order
    // build py2 sort keys (stable: payload = topk rank r); pads sort to end
    for (int r = t; r < CAND_CAP; r += SORT_THREADS) {
        if (r < (int)nreal) {
            unsigned int idx = (unsigned int)(sk[r] & 0xFFFFFFFFu);
            topidx[r] = idx;
            float4 b = boxes[idx];
            float py2 = (b.y + b.w) - 1.0f;
            sk[r] = ((unsigned long long)(~ford(py2)) << 32) | (unsigned long long)r;
        } else {
            sk[r] = ~0ull;
        }
    }
    __syncthreads();
    bitonic8192(sk, t);   // ascending => (py2 desc, stable by topk rank)
    for (int r2 = t; r2 < PRE_N; r2 += SORT_THREADS) {
        unsigned long long key = sk[r2];
        if (key == ~0ull) {                 // pad slot: inert zero box
            sP[r2] = make_float4(0.f, 0.f, 0.f, 0.f);
            sD[r2] = make_float4(0.f, 0.f, 0.f, 0.f);   // valid=0
        } else {
            unsigned int r = (unsigned int)(key & 0xFFFFFFFFu);
            float4 b = boxes[topidx[r]];
            float px2  = (b.x + b.z) - 1.0f;
            float py2s = (b.y + b.w) - 1.0f;
            float area = b.z * b.w;
            float valid = ((b.z >= 16.0f) && (b.w >= 16.0f)) ? 1.0f : 0.0f;
            sP[r2] = b;
            sD[r2] = make_float4(px2, py2s, area, valid);
        }
    }
}

__global__ void k_sup(const float4* __restrict__ sP,
                      const float4* __restrict__ sD,
                      unsigned long long* __restrict__ sup) {
    int t = blockIdx.x * blockDim.x + threadIdx.x;
    if (t >= PRE_N * NWORDS) return;
    int i = t % PRE_N;           // consecutive lanes -> consecutive i (coalesced)
    int w = t / PRE_N;
    float4 p  = sP[i];
    float4 dI = sD[i];
    unsigned long long bits = 0;
    int jbase = w * 64;
    int jend  = min(jbase + 64, PRE_N);
    for (int j = max(jbase, i + 1); j < jend; ++j) {
        float4 q  = sP[j];
        float4 dJ = sD[j];
        float iw = fmaxf(fminf(dI.x, dJ.x) - fmaxf(p.x, q.x) + 1.0f, 0.0f);
        float ih = fmaxf(fminf(dI.y, dJ.y) - fmaxf(p.y, q.y) + 1.0f, 0.0f);
        if (iw * ih >= 0.7f * dJ.z) bits |= 1ull << (j - jbase);
    }
    sup[(size_t)i * NWORDS + w] = bits;
}

__global__ void k_scan(const float4* __restrict__ sP,
                       const float4* __restrict__ sD,
                       const unsigned long long* __restrict__ sup,
                       float4* __restrict__ out) {
    int lane = threadIdx.x;   // single wave of 64
    unsigned long long rem0 = 0, rem1 = 0;  // removed-mask words lane, lane+64
    int kept = 0;
    for (int jb = 0; jb < PRE_N; jb += 64) {
        int j0 = jb + lane;
        float v = (j0 < PRE_N) ? sD[j0].w : 0.0f;   // OOB guard (tail block)
        unsigned long long vmask = __ballot(v != 0.0f);
        if (vmask == 0ull) continue;   // all-pad / all-invalid block: nothing can be kept
        int bend = min(64, PRE_N - jb);
        for (int b = 0; b < bend; ++b) {
            if (((vmask >> b) & 1ull) == 0) continue;
            int j = jb + b;
            int wj = j >> 6;
            unsigned long long wv = (wj < 64) ? __shfl(rem0, wj)
                                              : __shfl(rem1, wj - 64);
            bool removed = (wv >> (j & 63)) & 1ull;
            if (!removed) {
                if (lane == 0) out[kept] = sP[j];
                kept++;
                if (kept >= POST_N) return;
                rem0 |= sup[(size_t)j * NWORDS + lane];
                if (lane < NWORDS - 64) rem1 |= sup[(size_t)j * NWORDS + 64 + lane];
            }
        }
    }
}

extern "C" void kernel_launch(void* const* d_in, const int* in_sizes, int n_in,
                              void* d_out, int out_size, void* d_ws, size_t ws_size,
                              hipStream_t stream) {
    const float* scores  = (const float*)d_in[0];
    const float* deltas  = (const float*)d_in[1];
    const float* anchors = (const float*)d_in[2];
    char* ws = (char*)d_ws;

    float4*             boxes  = (float4*)(ws + OFF_BOXES);
    unsigned long long* keys   = (unsigned long long*)(ws + OFF_KEYS);
    unsigned int*       hist   = (unsigned int*)(ws + OFF_HIST);
    unsigned int*       meta   = (unsigned int*)(ws + OFF_META);
    unsigned long long* cand   = (unsigned long long*)(ws + OFF_CAND);
    unsigned int*       topidx = (unsigned int*)(ws + OFF_TIDX);
    float4*             sP     = (float4*)(ws + OFF_SP);
    float4*             sD     = (float4*)(ws + OFF_SD);
    unsigned long long* sup    = (unsigned long long*)(ws + OFF_SUP);

    // zero histogram + meta (incl. cand counter meta[2]) and output
    hipMemsetAsync(ws + OFF_HIST, 0, 65536 * 4 + 64, stream);
    hipMemsetAsync(d_out, 0, (size_t)POST_N * 4 * sizeof(float), stream);

    k_boxes<<<(NTOT + 255) / 256, 256, 0, stream>>>(scores, deltas, anchors,
                                                    boxes, keys, hist);
    k_findbin<<<1, 256, 0, stream>>>(hist, meta);
    k_compact<<<(NTOT + 255) / 256, 256, 0, stream>>>(keys, meta, cand, &meta[2]);
    k_sortbuild<<<1, SORT_THREADS, 0, stream>>>(boxes, meta, cand, topidx, sP, sD);
    k_sup<<<(PRE_N * NWORDS + 255) / 256, 256, 0, stream>>>(sP, sD, sup);
    k_scan<<<1, 64, 0, stream>>>(sP, sD, sup, (float4*)d_out);
}

// Round 4
// 405.412 us; speedup vs baseline: 1.8237x; 1.8237x over previous
//
#include <hip/hip_runtime.h>
#include <stdint.h>
#include <math.h>

#define NA 9
#define NTOT (9*128*128)         // 147456
#define PRE_N 6000
#define POST_N 300
#define CAND_CAP 8192
#define NWORDS 94                // ceil(6000/64)
#define SORT_THREADS 1024

typedef unsigned long long u64;

// ---- ws layout (bytes) ----
constexpr size_t OFF_BOXES = 0;                               // float4*NTOT = 2359296
constexpr size_t OFF_META  = OFF_BOXES + (size_t)NTOT * 16;   // 64 B
constexpr size_t OFF_CAND  = OFF_META + 64;                   // u64*CAND_CAP = 65536
constexpr size_t OFF_SP    = OFF_CAND + (size_t)CAND_CAP * 8; // float4*PRE_N = 96000
constexpr size_t OFF_SD    = OFF_SP + (size_t)PRE_N * 16;     // float4*PRE_N = 96000
constexpr size_t OFF_SUP   = OFF_SD + (size_t)PRE_N * 16;     // u64*PRE_N*NWORDS = 4512000

// monotone float -> uint (ascending order preserved, total order)
static __device__ __forceinline__ unsigned int ford(float f) {
    unsigned int b = __float_as_uint(f);
    return b ^ ((b & 0x80000000u) ? 0xFFFFFFFFu : 0x80000000u);
}

__global__ void k_boxes(const float* __restrict__ scores,
                        const float* __restrict__ deltas,
                        const float* __restrict__ anchors,
                        float4* __restrict__ boxes,
                        u64* __restrict__ cand,
                        unsigned int* __restrict__ cnt) {
    int i = blockIdx.x * blockDim.x + threadIdx.x;
    if (i >= NTOT) return;
    int a   = i >> 14;
    int rem = i & 16383;
    float4 d  = ((const float4*)deltas)[a * 16384 + rem]; // raw-reshape layout
    float4 an = ((const float4*)anchors)[i];
    float x1 = fmaxf(an.x + d.x, 0.0f);
    float y1 = fmaxf(an.y + d.y, 0.0f);
    float bw = fmaxf(an.z + d.z, 0.0f);
    float bh = fmaxf(an.w + d.w, 0.0f);
    float x2 = fminf(x1 + bw - 1.0f, 127.0f);   // uses pre-clamp x1
    float y2 = fminf(y1 + bh - 1.0f, 127.0f);
    x1 = fminf(x1, 127.0f);
    y1 = fminf(y1, 127.0f);
    bw = x2 - x1 + 1.0f;
    bh = y2 - y1 + 1.0f;
    boxes[i] = make_float4(x1, y1, bw, bh);
    bool valid = (bw >= 16.0f) && (bh >= 16.0f);
    // Only valid entries can ever reach the output (invalid score = -inf,
    // V=0 downstream). Append them all; the sort makes selection
    // deterministic (keys unique via idx payload).
    if (valid) {
        unsigned int inv = ~ford(scores[i]);    // ascending inv <=> score desc
        u64 key = ((u64)inv << 32) | (unsigned int)i;
        unsigned int p = atomicAdd(cnt, 1u);
        if (p < CAND_CAP) cand[p] = key;
    }
}

// dynamic-size bitonic sort, M = power of two, uniform across block
static __device__ void bitonic(u64* sk, int t, unsigned int M) {
    for (unsigned int k = 2; k <= M; k <<= 1) {
        for (unsigned int j = k >> 1; j > 0; j >>= 1) {
            for (unsigned int i = t; i < M; i += SORT_THREADS) {
                unsigned int l = i ^ j;
                if (l > i) {
                    u64 a = sk[i], b = sk[l];
                    bool up = ((i & k) == 0);
                    bool sw = up ? (a > b) : (a < b);
                    if (sw) { sk[i] = b; sk[l] = a; }
                }
            }
            __syncthreads();
        }
    }
}

__global__ void __launch_bounds__(SORT_THREADS)
k_sortbuild(const float4* __restrict__ boxes,
            const unsigned int* __restrict__ meta,
            const u64* __restrict__ cand,
            float4* __restrict__ sP, float4* __restrict__ sD) {
    __shared__ u64 sk[CAND_CAP];           // 64 KiB
    __shared__ unsigned int sidx[CAND_CAP];// 32 KiB (rank -> original idx)
    int t = threadIdx.x;
    unsigned int cnt = meta[2];
    if (cnt > CAND_CAP) cnt = CAND_CAP;
    unsigned int nreal = (cnt < PRE_N) ? cnt : PRE_N;
    unsigned int M = 2;
    while (M < cnt) M <<= 1;               // next pow2 >= cnt (uniform)
    for (unsigned int i = t; i < M; i += SORT_THREADS)
        sk[i] = (i < cnt) ? cand[i] : ~0ull;
    __syncthreads();
    bitonic(sk, t, M);    // ascending => (score desc, idx asc) = top_k order
    for (unsigned int r = t; r < M; r += SORT_THREADS) {
        if (r < nreal) {
            unsigned int idx = (unsigned int)(sk[r] & 0xFFFFFFFFu);
            sidx[r] = idx;
            float4 b = boxes[idx];
            float py2 = (b.y + b.w) - 1.0f;
            sk[r] = ((u64)(~ford(py2)) << 32) | (u64)r;
        } else {
            sk[r] = ~0ull;
        }
    }
    __syncthreads();
    bitonic(sk, t, M);    // ascending => (py2 desc, stable by topk rank)
    for (int r2 = t; r2 < PRE_N; r2 += SORT_THREADS) {
        bool real = (r2 < (int)M) && (sk[r2] != ~0ull);
        if (real) {
            unsigned int r = (unsigned int)(sk[r2] & 0xFFFFFFFFu);
            float4 b = boxes[sidx[r]];
            float px2  = (b.x + b.z) - 1.0f;
            float py2s = (b.y + b.w) - 1.0f;
            float area = b.z * b.w;
            float valid = ((b.z >= 16.0f) && (b.w >= 16.0f)) ? 1.0f : 0.0f;
            sP[r2] = b;
            sD[r2] = make_float4(px2, py2s, area, valid);
        } else {
            sP[r2] = make_float4(0.f, 0.f, 0.f, 0.f);
            sD[r2] = make_float4(0.f, 0.f, 0.f, 0.f);   // inert pad, valid=0
        }
    }
}

__global__ void k_sup(const float4* __restrict__ sP,
                      const float4* __restrict__ sD,
                      const unsigned int* __restrict__ meta,
                      u64* __restrict__ sup) {
    unsigned int cnt = meta[2];
    if (cnt > CAND_CAP) cnt = CAND_CAP;
    int nreal = (cnt < PRE_N) ? (int)cnt : PRE_N;
    int wreal = (nreal + 63) >> 6;
    int t = blockIdx.x * blockDim.x + threadIdx.x;
    if (t >= PRE_N * NWORDS) return;
    int i = t % PRE_N;           // consecutive lanes -> consecutive i (coalesced)
    int w = t / PRE_N;
    if (i >= nreal || w >= wreal) return;   // rows/words never read downstream
    float4 p  = sP[i];
    float4 dI = sD[i];
    u64 bits = 0;
    int jbase = w * 64;
    int jend  = min(jbase + 64, nreal);
    for (int j = max(jbase, i + 1); j < jend; ++j) {
        float4 q  = sP[j];
        float4 dJ = sD[j];
        float iw = fmaxf(fminf(dI.x, dJ.x) - fmaxf(p.x, q.x) + 1.0f, 0.0f);
        float ih = fmaxf(fminf(dI.y, dJ.y) - fmaxf(p.y, q.y) + 1.0f, 0.0f);
        if (iw * ih >= 0.7f * dJ.z) bits |= 1ull << (j - jbase);
    }
    sup[(size_t)i * NWORDS + w] = bits;
}

__global__ void k_scan(const float4* __restrict__ sP,
                       const float4* __restrict__ sD,
                       const u64* __restrict__ sup,
                       const unsigned int* __restrict__ meta,
                       float4* __restrict__ out) {
    int lane = threadIdx.x;   // single wave of 64
    unsigned int cnt = meta[2];
    if (cnt > CAND_CAP) cnt = CAND_CAP;
    int nreal = (cnt < PRE_N) ? (int)cnt : PRE_N;
    int wreal = (nreal + 63) >> 6;
    u64 rem0 = 0, rem1 = 0;  // removed-mask words lane, lane+64
    int kept = 0;
    for (int jb = 0; jb < nreal; jb += 64) {
        int j0 = jb + lane;
        float v = (j0 < nreal) ? sD[j0].w : 0.0f;
        u64 vmask = __ballot(v != 0.0f);
        if (vmask == 0ull) continue;
        int bend = min(64, nreal - jb);
        for (int b = 0; b < bend; ++b) {
            if (((vmask >> b) & 1ull) == 0) continue;
            int j = jb + b;
            int wj = j >> 6;
            u64 wv = (wj < 64) ? __shfl(rem0, wj) : __shfl(rem1, wj - 64);
            bool removed = (wv >> (j & 63)) & 1ull;
            if (!removed) {
                if (lane == 0) out[kept] = sP[j];
                kept++;
                if (kept >= POST_N) return;
                if (lane < wreal)      rem0 |= sup[(size_t)j * NWORDS + lane];
                if (64 + lane < wreal) rem1 |= sup[(size_t)j * NWORDS + 64 + lane];
            }
        }
    }
}

extern "C" void kernel_launch(void* const* d_in, const int* in_sizes, int n_in,
                              void* d_out, int out_size, void* d_ws, size_t ws_size,
                              hipStream_t stream) {
    const float* scores  = (const float*)d_in[0];
    const float* deltas  = (const float*)d_in[1];
    const float* anchors = (const float*)d_in[2];
    char* ws = (char*)d_ws;

    float4*       boxes = (float4*)(ws + OFF_BOXES);
    unsigned int* meta  = (unsigned int*)(ws + OFF_META);
    u64*          cand  = (u64*)(ws + OFF_CAND);
    float4*       sP    = (float4*)(ws + OFF_SP);
    float4*       sD    = (float4*)(ws + OFF_SD);
    u64*          sup   = (u64*)(ws + OFF_SUP);

    hipMemsetAsync(ws + OFF_META, 0, 64, stream);
    hipMemsetAsync(d_out, 0, (size_t)POST_N * 4 * sizeof(float), stream);

    k_boxes<<<(NTOT + 255) / 256, 256, 0, stream>>>(scores, deltas, anchors,
                                                    boxes, cand, &meta[2]);
    k_sortbuild<<<1, SORT_THREADS, 0, stream>>>(boxes, meta, cand, sP, sD);
    k_sup<<<(PRE_N * NWORDS + 255) / 256, 256, 0, stream>>>(sP, sD, meta, sup);
    k_scan<<<1, 64, 0, stream>>>(sP, sD, sup, meta, (float4*)d_out);
}

// Round 5
// 143.223 us; speedup vs baseline: 5.1623x; 2.8306x over previous
//
#include <hip/hip_runtime.h>
#include <stdint.h>
#include <math.h>

#define NA 9
#define NTOT (9*128*128)         // 147456
#define PRE_N 6000
#define POST_N 300
#define CAND_CAP 8192
#define NWORDS 94                // ceil(6000/64)
#define SORT_THREADS 1024

typedef unsigned long long u64;

// ---- ws layout (bytes) ----
constexpr size_t OFF_BOXES = 0;                               // float4*NTOT = 2359296
constexpr size_t OFF_META  = OFF_BOXES + (size_t)NTOT * 16;   // 64 B
constexpr size_t OFF_VM    = OFF_META + 64;                   // u64*NWORDS = 752 B (pad 768)
constexpr size_t OFF_CAND  = OFF_VM + 768;                    // u64*CAND_CAP = 65536
constexpr size_t OFF_SP    = OFF_CAND + (size_t)CAND_CAP * 8; // float4*PRE_N = 96000
constexpr size_t OFF_SD    = OFF_SP + (size_t)PRE_N * 16;     // float4*PRE_N = 96000
constexpr size_t OFF_SUP   = OFF_SD + (size_t)PRE_N * 16;     // u64*PRE_N*NWORDS = 4512000

// monotone float -> uint (ascending order preserved, total order)
static __device__ __forceinline__ unsigned int ford(float f) {
    unsigned int b = __float_as_uint(f);
    return b ^ ((b & 0x80000000u) ? 0xFFFFFFFFu : 0x80000000u);
}

__global__ void k_boxes(const float* __restrict__ scores,
                        const float* __restrict__ deltas,
                        const float* __restrict__ anchors,
                        float4* __restrict__ boxes,
                        u64* __restrict__ cand,
                        unsigned int* __restrict__ cnt) {
    int i = blockIdx.x * blockDim.x + threadIdx.x;
    if (i >= NTOT) return;
    int a   = i >> 14;
    int rem = i & 16383;
    float4 d  = ((const float4*)deltas)[a * 16384 + rem]; // raw-reshape layout
    float4 an = ((const float4*)anchors)[i];
    float x1 = fmaxf(an.x + d.x, 0.0f);
    float y1 = fmaxf(an.y + d.y, 0.0f);
    float bw = fmaxf(an.z + d.z, 0.0f);
    float bh = fmaxf(an.w + d.w, 0.0f);
    float x2 = fminf(x1 + bw - 1.0f, 127.0f);   // uses pre-clamp x1
    float y2 = fminf(y1 + bh - 1.0f, 127.0f);
    x1 = fminf(x1, 127.0f);
    y1 = fminf(y1, 127.0f);
    bw = x2 - x1 + 1.0f;
    bh = y2 - y1 + 1.0f;
    boxes[i] = make_float4(x1, y1, bw, bh);
    bool valid = (bw >= 16.0f) && (bh >= 16.0f);
    // Only valid entries can ever reach the output (invalid score = -inf,
    // V=0 downstream). Append them all; the sort makes selection
    // deterministic (keys unique via idx payload).
    if (valid) {
        unsigned int inv = ~ford(scores[i]);    // ascending inv <=> score desc
        u64 key = ((u64)inv << 32) | (unsigned int)i;
        unsigned int p = atomicAdd(cnt, 1u);
        if (p < CAND_CAP) cand[p] = key;
    }
}

// dynamic-size bitonic sort, M = power of two, uniform across block
static __device__ void bitonic(u64* sk, int t, unsigned int M) {
    for (unsigned int k = 2; k <= M; k <<= 1) {
        for (unsigned int j = k >> 1; j > 0; j >>= 1) {
            for (unsigned int i = t; i < M; i += SORT_THREADS) {
                unsigned int l = i ^ j;
                if (l > i) {
                    u64 a = sk[i], b = sk[l];
                    bool up = ((i & k) == 0);
                    bool sw = up ? (a > b) : (a < b);
                    if (sw) { sk[i] = b; sk[l] = a; }
                }
            }
            __syncthreads();
        }
    }
}

__global__ void __launch_bounds__(SORT_THREADS)
k_sortbuild(const float4* __restrict__ boxes,
            const unsigned int* __restrict__ meta,
            const u64* __restrict__ cand,
            float4* __restrict__ sP, float4* __restrict__ sD,
            u64* __restrict__ vmArr) {
    __shared__ u64 sk[CAND_CAP];           // 64 KiB
    __shared__ unsigned int sidx[CAND_CAP];// 32 KiB (rank -> original idx)
    int t = threadIdx.x;
    unsigned int cnt = meta[2];
    if (cnt > CAND_CAP) cnt = CAND_CAP;
    unsigned int nreal = (cnt < PRE_N) ? cnt : PRE_N;
    unsigned int M = 2;
    while (M < cnt) M <<= 1;               // next pow2 >= cnt (uniform)
    for (unsigned int i = t; i < M; i += SORT_THREADS)
        sk[i] = (i < cnt) ? cand[i] : ~0ull;
    __syncthreads();
    bitonic(sk, t, M);    // ascending => (score desc, idx asc) = top_k order
    for (unsigned int r = t; r < M; r += SORT_THREADS) {
        if (r < nreal) {
            unsigned int idx = (unsigned int)(sk[r] & 0xFFFFFFFFu);
            sidx[r] = idx;
            float4 b = boxes[idx];
            float py2 = (b.y + b.w) - 1.0f;
            sk[r] = ((u64)(~ford(py2)) << 32) | (u64)r;
        } else {
            sk[r] = ~0ull;
        }
    }
    __syncthreads();
    bitonic(sk, t, M);    // ascending => (py2 desc, stable by topk rank)
    for (int r2 = t; r2 < PRE_N; r2 += SORT_THREADS) {
        bool real = (r2 < (int)M) && (sk[r2] != ~0ull);
        float validf = 0.0f;
        if (real) {
            unsigned int r = (unsigned int)(sk[r2] & 0xFFFFFFFFu);
            float4 b = boxes[sidx[r]];
            float px2  = (b.x + b.z) - 1.0f;
            float py2s = (b.y + b.w) - 1.0f;
            float area = b.z * b.w;
            validf = ((b.z >= 16.0f) && (b.w >= 16.0f)) ? 1.0f : 0.0f;
            sP[r2] = b;
            sD[r2] = make_float4(px2, py2s, area, validf);
        } else {
            sP[r2] = make_float4(0.f, 0.f, 0.f, 0.f);
            sD[r2] = make_float4(0.f, 0.f, 0.f, 0.f);   // inert pad, valid=0
        }
        // validity bitmask: each wave covers exactly one 64-aligned word
        // (SORT_THREADS=1024, stride 1024 => word = (t>>6) + 16*iter)
        u64 bits = __ballot(validf != 0.0f);
        if ((t & 63) == 0) vmArr[r2 >> 6] = bits;
    }
}

__global__ void k_sup(const float4* __restrict__ sP,
                      const float4* __restrict__ sD,
                      const unsigned int* __restrict__ meta,
                      u64* __restrict__ sup) {
    unsigned int cnt = meta[2];
    if (cnt > CAND_CAP) cnt = CAND_CAP;
    int nreal = (cnt < PRE_N) ? (int)cnt : PRE_N;
    int wreal = (nreal + 63) >> 6;
    int t = blockIdx.x * blockDim.x + threadIdx.x;
    if (t >= PRE_N * NWORDS) return;
    int i = t % PRE_N;           // consecutive lanes -> consecutive i (coalesced)
    int w = t / PRE_N;
    if (i >= nreal || w >= wreal) return;   // rows/words never read downstream
    float4 p  = sP[i];
    float4 dI = sD[i];
    u64 bits = 0;
    int jbase = w * 64;
    int jend  = min(jbase + 64, nreal);
    for (int j = max(jbase, i + 1); j < jend; ++j) {
        float4 q  = sP[j];
        float4 dJ = sD[j];
        float iw = fmaxf(fminf(dI.x, dJ.x) - fmaxf(p.x, q.x) + 1.0f, 0.0f);
        float ih = fmaxf(fminf(dI.y, dJ.y) - fmaxf(p.y, q.y) + 1.0f, 0.0f);
        if (iw * ih >= 0.7f * dJ.z) bits |= 1ull << (j - jbase);
    }
    sup[(size_t)i * NWORDS + w] = bits;
}

// Per-KEEP serial scan: removal state changes only when a box is kept, so the
// dependent chain is keeps (~300), not candidates (~6000).
__global__ void k_scan(const float4* __restrict__ sP,
                       const u64* __restrict__ vmArr,
                       const u64* __restrict__ sup,
                       const unsigned int* __restrict__ meta,
                       float4* __restrict__ out) {
    int lane = threadIdx.x;   // single wave of 64
    unsigned int cnt = meta[2];
    if (cnt > CAND_CAP) cnt = CAND_CAP;
    int nreal = (cnt < PRE_N) ? (int)cnt : PRE_N;
    int nblk = (nreal + 63) >> 6;
    // lane l holds validity word l and removed word l (l, l+64)
    u64 vm0 = (lane < nblk)      ? vmArr[lane]      : 0ull;
    u64 vm1 = (64 + lane < nblk) ? vmArr[64 + lane] : 0ull;
    u64 rem0 = 0, rem1 = 0;
    int kept = 0;
    for (int w = 0; w < nblk; ++w) {
        u64 live = (w < 64) ? (__shfl(vm0, w) & ~__shfl(rem0, w))
                            : (__shfl(vm1, w - 64) & ~__shfl(rem1, w - 64));
        while (live) {
            int b = __ffsll(live) - 1;
            int j = (w << 6) + b;
            if (lane == 0) out[kept] = sP[j];
            kept++;
            if (kept >= POST_N) goto done;
            // suppression row of the kept box (coalesced: lane l -> word l)
            u64 s0 = (lane < nblk)      ? sup[(size_t)j * NWORDS + lane]      : 0ull;
            u64 s1 = (64 + lane < nblk) ? sup[(size_t)j * NWORDS + 64 + lane] : 0ull;
            rem0 |= s0;
            rem1 |= s1;
            u64 sw = (w < 64) ? __shfl(s0, w) : __shfl(s1, w - 64);
            live &= ~(1ull << b);   // row never has its own bit (strict i<j)
            live &= ~sw;
        }
    }
done:
    // zero-fill remaining output rows (replaces a memset dispatch)
    for (int r = kept + lane; r < POST_N; r += 64)
        out[r] = make_float4(0.f, 0.f, 0.f, 0.f);
}

extern "C" void kernel_launch(void* const* d_in, const int* in_sizes, int n_in,
                              void* d_out, int out_size, void* d_ws, size_t ws_size,
                              hipStream_t stream) {
    const float* scores  = (const float*)d_in[0];
    const float* deltas  = (const float*)d_in[1];
    const float* anchors = (const float*)d_in[2];
    char* ws = (char*)d_ws;

    float4*       boxes = (float4*)(ws + OFF_BOXES);
    unsigned int* meta  = (unsigned int*)(ws + OFF_META);
    u64*          vm    = (u64*)(ws + OFF_VM);
    u64*          cand  = (u64*)(ws + OFF_CAND);
    float4*       sP    = (float4*)(ws + OFF_SP);
    float4*       sD    = (float4*)(ws + OFF_SD);
    u64*          sup   = (u64*)(ws + OFF_SUP);

    hipMemsetAsync(ws + OFF_META, 0, 64, stream);   // zero cand counter

    k_boxes<<<(NTOT + 255) / 256, 256, 0, stream>>>(scores, deltas, anchors,
                                                    boxes, cand, &meta[2]);
    k_sortbuild<<<1, SORT_THREADS, 0, stream>>>(boxes, meta, cand, sP, sD, vm);
    k_sup<<<(PRE_N * NWORDS + 255) / 256, 256, 0, stream>>>(sP, sD, meta, sup);
    k_scan<<<1, 64, 0, stream>>>(sP, vm, sup, meta, (float4*)d_out);
}